// Round 1
// baseline (1133.751 us; speedup 1.0000x reference)
//
#include <hip/hip_runtime.h>
#include <math.h>

#define NEG_SLOPE 0.2f

__device__ __forceinline__ float lrelu(float x) {
    // for x>=0: max(x, 0.2x)=x ; for x<0: max(x,0.2x)=0.2x
    return fmaxf(x, NEG_SLOPE * x);
}

// Fused conv3d(3x3x3, pad=1) + bias + maxpool(2x2x2) + LeakyReLU.
// One thread = one pooled output position (zp,yp,xp) x OPT output channels.
// tid layout: og slowest, then b, then pos (pos fastest => coalesced stores,
// og wave-uniform => weight loads become scalar loads).
template<int CI, int CO, int S, int OPT>
__global__ __launch_bounds__(256) void conv_pool_lrelu(
    const float* __restrict__ in,   // [B, CI, S, S, S]
    const float* __restrict__ w,    // [CO, CI, 3, 3, 3]
    const float* __restrict__ bias, // [CO]
    float* __restrict__ out,        // [B, CO, S/2, S/2, S/2]
    int B)
{
    constexpr int SP   = S / 2;
    constexpr int NPOS = SP * SP * SP;
    constexpr int NOG  = CO / OPT;

    const int tid   = blockIdx.x * 256 + threadIdx.x;
    const int total = NOG * B * NPOS;
    if (tid >= total) return;

    const int pos = tid % NPOS;
    const int b   = (tid / NPOS) % B;
    const int og  = tid / (NPOS * B);

    const int xp = pos % SP;
    const int yp = (pos / SP) % SP;
    const int zp = pos / (SP * SP);
    const int gz0 = 2 * zp - 1, gy0 = 2 * yp - 1, gx0 = 2 * xp - 1;

    float acc[OPT][8];
#pragma unroll
    for (int oo = 0; oo < OPT; ++oo)
#pragma unroll
        for (int p = 0; p < 8; ++p) acc[oo][p] = 0.f;

#pragma unroll 1
    for (int ci = 0; ci < CI; ++ci) {
        const float* inb = in + (long)(b * CI + ci) * (S * S * S);
        // 4x4x4 input region covering all 8 conv positions of the pool window
        float v[4][4][4];
#pragma unroll
        for (int dz = 0; dz < 4; ++dz) {
            const int gz = gz0 + dz;
            const bool bz = (unsigned)gz < (unsigned)S;
#pragma unroll
            for (int dy = 0; dy < 4; ++dy) {
                const int gy = gy0 + dy;
                const bool by = (unsigned)gy < (unsigned)S;
#pragma unroll
                for (int dx = 0; dx < 4; ++dx) {
                    const int gx = gx0 + dx;
                    const bool bx = (unsigned)gx < (unsigned)S;
                    v[dz][dy][dx] = (bz && by && bx)
                        ? inb[gz * S * S + gy * S + gx] : 0.f;
                }
            }
        }
#pragma unroll
        for (int oo = 0; oo < OPT; ++oo) {
            const int o = og * OPT + oo;
            const float* wp = w + (long)(o * CI + ci) * 27;
#pragma unroll
            for (int kz = 0; kz < 3; ++kz)
#pragma unroll
                for (int ky = 0; ky < 3; ++ky)
#pragma unroll
                    for (int kx = 0; kx < 3; ++kx) {
                        const float wv = wp[kz * 9 + ky * 3 + kx];
#pragma unroll
                        for (int pz = 0; pz < 2; ++pz)
#pragma unroll
                            for (int py = 0; py < 2; ++py)
#pragma unroll
                                for (int px = 0; px < 2; ++px)
                                    acc[oo][pz * 4 + py * 2 + px] +=
                                        v[pz + kz][py + ky][px + kx] * wv;
                    }
        }
    }

#pragma unroll
    for (int oo = 0; oo < OPT; ++oo) {
        const int o = og * OPT + oo;
        float m = acc[oo][0];
#pragma unroll
        for (int p = 1; p < 8; ++p) m = fmaxf(m, acc[oo][p]);
        m += bias[o];
        out[(long)(b * CO + o) * NPOS + pos] = lrelu(m);
    }
}

// 6 parallel heads: [B,64] -> 32 -> 16 -> 4, lrelu each, then L2-normalize.
__global__ __launch_bounds__(256) void fc_heads(
    const float* __restrict__ feat, // [B, 64]
    const float* __restrict__ W1, const float* __restrict__ b1, // [6,64,32],[6,32]
    const float* __restrict__ W2, const float* __restrict__ b2, // [6,32,16],[6,16]
    const float* __restrict__ W3, const float* __restrict__ b3, // [6,16,4],[6,4]
    float* __restrict__ out, // [B, 6, 4]
    int B)
{
    const int tid = blockIdx.x * 256 + threadIdx.x;
    if (tid >= 6 * B) return;
    const int b = tid % B;
    const int h = tid / B;  // wave-uniform (B multiple of 256)

    float f[64];
#pragma unroll
    for (int k = 0; k < 64; ++k) f[k] = feat[b * 64 + k];

    float h1[32];
#pragma unroll 1
    for (int j = 0; j < 32; ++j) {
        float s = b1[h * 32 + j];
#pragma unroll
        for (int k = 0; k < 64; ++k) s += f[k] * W1[(h * 64 + k) * 32 + j];
        h1[j] = lrelu(s);
    }
    float h2[16];
#pragma unroll 1
    for (int j = 0; j < 16; ++j) {
        float s = b2[h * 16 + j];
#pragma unroll
        for (int k = 0; k < 32; ++k) s += h1[k] * W2[(h * 32 + k) * 16 + j];
        h2[j] = lrelu(s);
    }
    float h3[4];
#pragma unroll
    for (int j = 0; j < 4; ++j) {
        float s = b3[h * 4 + j];
#pragma unroll
        for (int k = 0; k < 16; ++k) s += h2[k] * W3[(h * 16 + k) * 4 + j];
        h3[j] = lrelu(s);
    }
    const float n = sqrtf(h3[0] * h3[0] + h3[1] * h3[1] +
                          h3[2] * h3[2] + h3[3] * h3[3]);
    const float inv = 1.f / n;
#pragma unroll
    for (int q = 0; q < 4; ++q) out[(b * 6 + h) * 4 + q] = h3[q] * inv;
}

extern "C" void kernel_launch(void* const* d_in, const int* in_sizes, int n_in,
                              void* d_out, int out_size, void* d_ws, size_t ws_size,
                              hipStream_t stream)
{
    const float* voxel = (const float*)d_in[0];
    const float* cw1 = (const float*)d_in[1];  const float* cb1 = (const float*)d_in[2];
    const float* cw2 = (const float*)d_in[3];  const float* cb2 = (const float*)d_in[4];
    const float* cw3 = (const float*)d_in[5];  const float* cb3 = (const float*)d_in[6];
    const float* cw4 = (const float*)d_in[7];  const float* cb4 = (const float*)d_in[8];
    const float* cw5 = (const float*)d_in[9];  const float* cb5 = (const float*)d_in[10];
    const float* W1  = (const float*)d_in[11]; const float* b1  = (const float*)d_in[12];
    const float* W2  = (const float*)d_in[13]; const float* b2  = (const float*)d_in[14];
    const float* W3  = (const float*)d_in[15]; const float* b3  = (const float*)d_in[16];
    float* out = (float*)d_out;

    const int B = 1024;
    float* buf1 = (float*)d_ws;              // [B,4,16^3]  = 16777216 floats
    float* buf2 = buf1 + 16777216;           // [B,8,8^3]   =  4194304 floats
    float* buf3 = buf2 + 4194304;            // [B,16,4^3]  =  1048576 floats
    float* buf4 = buf3 + 1048576;            // [B,32,2^3]  =   262144 floats
    float* buf5 = buf4 + 262144;             // [B,64]      =    65536 floats

    // L1: 1->4, 32^3 -> 16^3. NOG=1, total = 1024*4096 = 4194304 threads
    conv_pool_lrelu<1, 4, 32, 4><<<16384, 256, 0, stream>>>(voxel, cw1, cb1, buf1, B);
    // L2: 4->8, 16^3 -> 8^3. OPT=4, NOG=2, total = 2*1024*512 = 1048576
    conv_pool_lrelu<4, 8, 16, 4><<<4096, 256, 0, stream>>>(buf1, cw2, cb2, buf2, B);
    // L3: 8->16, 8^3 -> 4^3. OPT=4, NOG=4, total = 4*1024*64 = 262144
    conv_pool_lrelu<8, 16, 8, 4><<<1024, 256, 0, stream>>>(buf2, cw3, cb3, buf3, B);
    // L4: 16->32, 4^3 -> 2^3. OPT=2, NOG=16, total = 16*1024*8 = 131072
    conv_pool_lrelu<16, 32, 4, 2><<<512, 256, 0, stream>>>(buf3, cw4, cb4, buf4, B);
    // L5: 32->64, 2^3 -> 1^3. OPT=2, NOG=32, total = 32*1024*1 = 32768
    conv_pool_lrelu<32, 64, 2, 2><<<128, 256, 0, stream>>>(buf4, cw5, cb5, buf5, B);
    // FC heads: 6*1024 = 6144 threads
    fc_heads<<<24, 256, 0, stream>>>(buf5, W1, b1, W2, b2, W3, b3, out, B);
}

// Round 2
// 791.872 us; speedup vs baseline: 1.4317x; 1.4317x over previous
//
#include <hip/hip_runtime.h>
#include <math.h>

#define NEG_SLOPE 0.2f

__device__ __forceinline__ float lrelu(float x) {
    return fmaxf(x, NEG_SLOPE * x);
}

// Fused conv3d(3x3x3,pad=1) + bias + maxpool(2x2x2) + LeakyReLU, LDS-staged.
// Block = (b, pooled-z-slab of ZT). LDS holds [CI][2ZT+2][S+2][S+2] with
// ZERO-PADDED borders -> compute loop has NO bounds checks, reads LDS only.
// Thread = 1 pooled position x CPT output channels. Requires
// (CO/CPT) * (ZT*SP*SP) == 256. og = t / NPOS_BLK is wave-uniform for L1-L3.
template<int CI, int CO, int S, int ZT, int CPT>
__global__ __launch_bounds__(256) void conv_pool_lrelu_lds(
    const float* __restrict__ in,   // [B, CI, S,S,S]
    const float* __restrict__ w,    // [CO, CI, 3,3,3]
    const float* __restrict__ bias, // [CO]
    float* __restrict__ out,        // [B, CO, S/2,S/2,S/2]
    int B)
{
    constexpr int SP = S / 2;
    constexpr int ZD = 2 * ZT + 2;          // LDS z planes (incl halo)
    constexpr int RS = S + 2;               // padded row size
    constexpr int LDS_N = CI * ZD * RS * RS;
    constexpr int NPOS_BLK = ZT * SP * SP;
    constexpr int NOG = CO / CPT;
    static_assert(NOG * NPOS_BLK == 256, "thread mapping must cover block");

    __shared__ float sm[LDS_N];

    const int t = threadIdx.x;
    constexpr int NSLAB = SP / ZT;
    const int b = blockIdx.x / NSLAB;
    const int zslab = blockIdx.x % NSLAB;
    const int zp0 = zslab * ZT;
    const int gz0 = 2 * zp0 - 1;            // global z of LDS plane 0

    // ---- fill LDS (zero halo) ----
    for (int i = t; i < LDS_N; i += 256) {
        const int x = i % RS;
        const int y = (i / RS) % RS;
        const int z = (i / (RS * RS)) % ZD;
        const int ci = i / (RS * RS * ZD);
        const int gx = x - 1, gy = y - 1, gz = gz0 + z;
        float v = 0.f;
        if ((unsigned)gx < (unsigned)S && (unsigned)gy < (unsigned)S &&
            (unsigned)gz < (unsigned)S)
            v = in[(long)(b * CI + ci) * (S * S * S) + (gz * S + gy) * S + gx];
        sm[i] = v;
    }
    __syncthreads();

    // ---- compute ----
    const int pos = t % NPOS_BLK;
    const int og  = t / NPOS_BLK;
    const int xp = pos % SP;
    const int yp = (pos / SP) % SP;
    const int zl = pos / (SP * SP);

    float acc[CPT][8];
#pragma unroll
    for (int oo = 0; oo < CPT; ++oo)
#pragma unroll
        for (int p = 0; p < 8; ++p) acc[oo][p] = 0.f;

#pragma unroll 1
    for (int ci = 0; ci < CI; ++ci) {
        const float* sp_ = &sm[((ci * ZD + 2 * zl) * RS + 2 * yp) * RS + 2 * xp];
        float v[4][4][4];
#pragma unroll
        for (int dz = 0; dz < 4; ++dz)
#pragma unroll
            for (int dy = 0; dy < 4; ++dy)
#pragma unroll
                for (int dx = 0; dx < 4; ++dx)
                    v[dz][dy][dx] = sp_[(dz * RS + dy) * RS + dx];
#pragma unroll
        for (int oo = 0; oo < CPT; ++oo) {
            const float* wp = w + (long)((og * CPT + oo) * CI + ci) * 27;
#pragma unroll
            for (int kz = 0; kz < 3; ++kz)
#pragma unroll
                for (int ky = 0; ky < 3; ++ky)
#pragma unroll
                    for (int kx = 0; kx < 3; ++kx) {
                        const float wv = wp[kz * 9 + ky * 3 + kx];
#pragma unroll
                        for (int pz = 0; pz < 2; ++pz)
#pragma unroll
                            for (int py = 0; py < 2; ++py)
#pragma unroll
                                for (int px = 0; px < 2; ++px)
                                    acc[oo][pz * 4 + py * 2 + px] +=
                                        v[pz + kz][py + ky][px + kx] * wv;
                    }
        }
    }

#pragma unroll
    for (int oo = 0; oo < CPT; ++oo) {
        const int o = og * CPT + oo;
        float m = acc[oo][0];
#pragma unroll
        for (int p = 1; p < 8; ++p) m = fmaxf(m, acc[oo][p]);
        m += bias[o];
        out[(long)(b * CO + o) * (SP * SP * SP) +
            ((zp0 + zl) * SP + yp) * SP + xp] = lrelu(m);
    }
}

// Layer 5: CI=32, S=2 -> out [B,64]. 4 batches per block; region reads are
// wave-uniform (all 64 lanes of a wave share bl) -> LDS broadcast, free.
__global__ __launch_bounds__(256) void conv_pool_lrelu_l5(
    const float* __restrict__ in,   // [B,32,2,2,2]
    const float* __restrict__ w,    // [64,32,3,3,3]
    const float* __restrict__ bias, // [64]
    float* __restrict__ out,        // [B,64]
    int B)
{
    constexpr int CI = 32;
    __shared__ float sm[4 * CI * 64];  // 4 b x 32 ci x 4x4x4 padded = 32 KB
    const int t = threadIdx.x;
    const int b0 = blockIdx.x * 4;

    for (int i = t; i < 4 * CI * 64; i += 256) {
        const int x = i % 4;
        const int y = (i / 4) % 4;
        const int z = (i / 16) % 4;
        const int ci = (i / 64) % CI;
        const int bl = i / (64 * CI);
        const int gx = x - 1, gy = y - 1, gz = z - 1;
        float v = 0.f;
        if ((unsigned)gx < 2u && (unsigned)gy < 2u && (unsigned)gz < 2u)
            v = in[((b0 + bl) * CI + ci) * 8 + (gz * 2 + gy) * 2 + gx];
        sm[i] = v;
    }
    __syncthreads();

    const int co = t % 64;
    const int bl = t / 64;
    float acc[8];
#pragma unroll
    for (int p = 0; p < 8; ++p) acc[p] = 0.f;

#pragma unroll 1
    for (int ci = 0; ci < CI; ++ci) {
        const float* sp_ = &sm[(bl * CI + ci) * 64];
        float v[4][4][4];
#pragma unroll
        for (int dz = 0; dz < 4; ++dz)
#pragma unroll
            for (int dy = 0; dy < 4; ++dy)
#pragma unroll
                for (int dx = 0; dx < 4; ++dx)
                    v[dz][dy][dx] = sp_[(dz * 4 + dy) * 4 + dx];
        const float* wp = w + (long)(co * CI + ci) * 27;
#pragma unroll
        for (int kz = 0; kz < 3; ++kz)
#pragma unroll
            for (int ky = 0; ky < 3; ++ky)
#pragma unroll
                for (int kx = 0; kx < 3; ++kx) {
                    const float wv = wp[kz * 9 + ky * 3 + kx];
#pragma unroll
                    for (int pz = 0; pz < 2; ++pz)
#pragma unroll
                        for (int py = 0; py < 2; ++py)
#pragma unroll
                            for (int px = 0; px < 2; ++px)
                                acc[pz * 4 + py * 2 + px] +=
                                    v[pz + kz][py + ky][px + kx] * wv;
                }
    }

    float m = acc[0];
#pragma unroll
    for (int p = 1; p < 8; ++p) m = fmaxf(m, acc[p]);
    m += bias[co];
    out[(b0 + bl) * 64 + co] = lrelu(m);
}

// 6 parallel heads: [B,64] -> 32 -> 16 -> 4, lrelu each, then L2-normalize.
__global__ __launch_bounds__(256) void fc_heads(
    const float* __restrict__ feat,
    const float* __restrict__ W1, const float* __restrict__ b1,
    const float* __restrict__ W2, const float* __restrict__ b2,
    const float* __restrict__ W3, const float* __restrict__ b3,
    float* __restrict__ out, int B)
{
    const int tid = blockIdx.x * 256 + threadIdx.x;
    if (tid >= 6 * B) return;
    const int b = tid % B;
    const int h = tid / B;

    float f[64];
#pragma unroll
    for (int k = 0; k < 64; ++k) f[k] = feat[b * 64 + k];

    float h1[32];
#pragma unroll 1
    for (int j = 0; j < 32; ++j) {
        float s = b1[h * 32 + j];
#pragma unroll
        for (int k = 0; k < 64; ++k) s += f[k] * W1[(h * 64 + k) * 32 + j];
        h1[j] = lrelu(s);
    }
    float h2[16];
#pragma unroll 1
    for (int j = 0; j < 16; ++j) {
        float s = b2[h * 16 + j];
#pragma unroll
        for (int k = 0; k < 32; ++k) s += h1[k] * W2[(h * 32 + k) * 16 + j];
        h2[j] = lrelu(s);
    }
    float h3[4];
#pragma unroll
    for (int j = 0; j < 4; ++j) {
        float s = b3[h * 4 + j];
#pragma unroll
        for (int k = 0; k < 16; ++k) s += h2[k] * W3[(h * 16 + k) * 4 + j];
        h3[j] = lrelu(s);
    }
    const float n = sqrtf(h3[0] * h3[0] + h3[1] * h3[1] +
                          h3[2] * h3[2] + h3[3] * h3[3]);
    const float inv = 1.f / n;
#pragma unroll
    for (int q = 0; q < 4; ++q) out[(b * 6 + h) * 4 + q] = h3[q] * inv;
}

extern "C" void kernel_launch(void* const* d_in, const int* in_sizes, int n_in,
                              void* d_out, int out_size, void* d_ws, size_t ws_size,
                              hipStream_t stream)
{
    const float* voxel = (const float*)d_in[0];
    const float* cw1 = (const float*)d_in[1];  const float* cb1 = (const float*)d_in[2];
    const float* cw2 = (const float*)d_in[3];  const float* cb2 = (const float*)d_in[4];
    const float* cw3 = (const float*)d_in[5];  const float* cb3 = (const float*)d_in[6];
    const float* cw4 = (const float*)d_in[7];  const float* cb4 = (const float*)d_in[8];
    const float* cw5 = (const float*)d_in[9];  const float* cb5 = (const float*)d_in[10];
    const float* W1  = (const float*)d_in[11]; const float* b1  = (const float*)d_in[12];
    const float* W2  = (const float*)d_in[13]; const float* b2  = (const float*)d_in[14];
    const float* W3  = (const float*)d_in[15]; const float* b3  = (const float*)d_in[16];
    float* out = (float*)d_out;

    const int B = 1024;
    float* buf1 = (float*)d_ws;              // [B,4,16^3]
    float* buf2 = buf1 + 16777216;           // [B,8,8^3]
    float* buf3 = buf2 + 4194304;            // [B,16,4^3]
    float* buf4 = buf3 + 1048576;            // [B,32,2^3]
    float* buf5 = buf4 + 262144;             // [B,64]

    // L1: 1->4, 32^3->16^3. ZT=1 -> 16 slabs/b. (CO/CPT)*(ZT*16*16)=1*256 ✓
    conv_pool_lrelu_lds<1, 4, 32, 1, 4><<<1024 * 16, 256, 0, stream>>>(voxel, cw1, cb1, buf1, B);
    // L2: 4->8, 16^3->8^3. ZT=2 -> 4 slabs/b. 2*(2*8*8)=2*128=256 ✓
    conv_pool_lrelu_lds<4, 8, 16, 2, 4><<<1024 * 4, 256, 0, stream>>>(buf1, cw2, cb2, buf2, B);
    // L3: 8->16, 8^3->4^3. ZT=4 (full). 4*(4*4*4)=4*64=256 ✓
    conv_pool_lrelu_lds<8, 16, 8, 4, 4><<<1024, 256, 0, stream>>>(buf2, cw3, cb3, buf3, B);
    // L4: 16->32, 4^3->2^3. ZT=2 (full). 32*(2*2*2)=32*8=256 ✓
    conv_pool_lrelu_lds<16, 32, 4, 2, 1><<<1024, 256, 0, stream>>>(buf3, cw4, cb4, buf4, B);
    // L5: 32->64, 2^3->1. 4 b/block.
    conv_pool_lrelu_l5<<<256, 256, 0, stream>>>(buf4, cw5, cb5, buf5, B);
    // FC heads
    fc_heads<<<24, 256, 0, stream>>>(buf5, W1, b1, W2, b2, W3, b3, out, B);
}

// Round 3
// 642.753 us; speedup vs baseline: 1.7639x; 1.2320x over previous
//
#include <hip/hip_runtime.h>
#include <math.h>

#define NEG_SLOPE 0.2f

__device__ __forceinline__ float lrelu(float x) {
    return fmaxf(x, NEG_SLOPE * x);
}

constexpr int clog2(int n) { return (n <= 1) ? 0 : 1 + clog2(n / 2); }

// Fused conv3d(3x3x3,pad=1) + bias + maxpool(2x2x2) + LeakyReLU, LDS-staged.
// v3: div-free vectorized fill (phase A zero + phase B interior float4),
// x-padded rows (XOFF=5, XR=S+8 -> even read bases, 16B-aligned row stride),
// PZT pooled-z per thread (fill amortization), BPB batches per block.
// Mapping: 256 threads = BPB * (CO/CPT) * ((ZT/PZT)*SP*SP).
template<int CI, int CO, int S, int ZT, int PZT, int CPT, int BPB>
__global__ __launch_bounds__(256) void conv_pool_lds2(
    const float* __restrict__ in,   // [B, CI, S,S,S]
    const float* __restrict__ w,    // [CO, CI, 3,3,3]
    const float* __restrict__ bias, // [CO]
    float* __restrict__ out,        // [B, CO, SP,SP,SP]
    int B)
{
    constexpr int SP    = S / 2;
    constexpr int ZD    = 2 * ZT + 2;        // staged z planes incl halo
    constexpr int YS    = S + 2;             // rows per plane incl halo
    constexpr int XOFF  = 5;                 // gx -> x = gx + XOFF (reads even)
    constexpr int XR    = S + 8;             // padded row stride (mult of 4)
    constexpr int PLANE = YS * XR;
    constexpr int NPAIR = BPB * CI * ZD;     // total staged planes
    constexpr int LDS_N = NPAIR * PLANE;
    constexpr int NOG   = CO / CPT;
    constexpr int NZB   = ZT / PZT;
    constexpr int NPOS  = NZB * SP * SP;
    constexpr int NSLAB = SP / ZT;
    static_assert(BPB * NOG * NPOS == 256, "thread mapping must cover block");
    static_assert((LDS_N & 3) == 0, "float4 zero");

    __shared__ __align__(16) float sm[LDS_N];

    const int t     = threadIdx.x;
    const int zslab = blockIdx.x & (NSLAB - 1);
    const int b0    = (blockIdx.x >> clog2(NSLAB)) * BPB;
    const int zp0   = zslab * ZT;
    const int gz0   = 2 * zp0 - 1;           // global z of LDS plane 0

    // ---- Phase A: zero all of LDS (covers halos + invalid planes) ----
    {
        float4* s4 = (float4*)sm;
        constexpr int N4 = LDS_N / 4;
#pragma unroll
        for (int i = 0; i < (N4 + 255) / 256; ++i) {
            const int k = t + i * 256;
            if (k < N4) s4[k] = make_float4(0.f, 0.f, 0.f, 0.f);
        }
    }
    __syncthreads();

    // ---- Phase B: interior rows, float4 global loads, div-free indexing ----
    {
        constexpr int CHUNKS = S / 4;            // float4 chunks per row
        constexpr int PJOBS  = S * CHUNKS;       // jobs per plane
        constexpr int PPI    = 256 / PJOBS;      // planes per iteration
        constexpr int FITER  = NPAIR / PPI;
        static_assert(FITER * PPI == NPAIR, "fill covers planes exactly");
        const int idx  = t & (PJOBS - 1);
        const int poff = t >> clog2(PJOBS);
        const int cc   = idx & (CHUNKS - 1);     // x chunk
        const int yy   = idx >> clog2(CHUNKS);   // gy
#pragma unroll
        for (int it = 0; it < FITER; ++it) {
            const int plane = it * PPI + poff;   // = (bl*CI+ci)*ZD + z
            const int z     = plane % ZD;        // const divisor -> magic mul
            const int bci   = plane / ZD;        // bl*CI + ci
            const int gz    = gz0 + z;
            if ((unsigned)gz < (unsigned)S) {
                const float4 v = *(const float4*)&in[
                    ((long)(b0 * CI + bci) * S + gz) * (S * S) + yy * S + 4 * cc];
                float* sp = &sm[(plane * YS + (yy + 1)) * XR + XOFF + 4 * cc];
                sp[0] = v.x; sp[1] = v.y; sp[2] = v.z; sp[3] = v.w;
            }
        }
    }
    __syncthreads();

    // ---- Compute ----
    const int pos = t & (NPOS - 1);
    const int og  = (t >> clog2(NPOS)) & (NOG - 1);
    const int bl  = t >> clog2(NPOS * NOG);
    const int xp  = pos & (SP - 1);
    const int yp  = (pos >> clog2(SP)) & (SP - 1);
    const int zb  = pos >> (2 * clog2(SP));

#pragma unroll
    for (int zi = 0; zi < PZT; ++zi) {
        const int zl = zb * PZT + zi;            // pooled z within block
        float acc[CPT][8];
#pragma unroll
        for (int oo = 0; oo < CPT; ++oo)
#pragma unroll
            for (int p = 0; p < 8; ++p) acc[oo][p] = 0.f;

#pragma unroll 1
        for (int ci = 0; ci < CI; ++ci) {
            const float* sp_ = &sm[((bl * CI + ci) * ZD + 2 * zl) * PLANE +
                                   (2 * yp) * XR + 2 * xp + (XOFF - 1)];
            float v[4][4][4];
#pragma unroll
            for (int dz = 0; dz < 4; ++dz)
#pragma unroll
                for (int dy = 0; dy < 4; ++dy)
#pragma unroll
                    for (int dx = 0; dx < 4; ++dx)
                        v[dz][dy][dx] = sp_[dz * PLANE + dy * XR + dx];
#pragma unroll
            for (int oo = 0; oo < CPT; ++oo) {
                const float* wp = w + (long)((og * CPT + oo) * CI + ci) * 27;
#pragma unroll
                for (int kz = 0; kz < 3; ++kz)
#pragma unroll
                    for (int ky = 0; ky < 3; ++ky)
#pragma unroll
                        for (int kx = 0; kx < 3; ++kx) {
                            const float wv = wp[kz * 9 + ky * 3 + kx];
#pragma unroll
                            for (int pz = 0; pz < 2; ++pz)
#pragma unroll
                                for (int py = 0; py < 2; ++py)
#pragma unroll
                                    for (int px = 0; px < 2; ++px)
                                        acc[oo][pz * 4 + py * 2 + px] +=
                                            v[pz + kz][py + ky][px + kx] * wv;
                        }
            }
        }

#pragma unroll
        for (int oo = 0; oo < CPT; ++oo) {
            const int o = og * CPT + oo;
            float m = acc[oo][0];
#pragma unroll
            for (int p = 1; p < 8; ++p) m = fmaxf(m, acc[oo][p]);
            m += bias[o];
            out[(long)((b0 + bl) * CO + o) * (SP * SP * SP) +
                ((zp0 + zl) * SP + yp) * SP + xp] = lrelu(m);
        }
    }
}

// Layer 5: CI=32, S=2 -> out [B,64]. 4 batches per block; region reads are
// wave-uniform -> LDS broadcast, conflict-free.
__global__ __launch_bounds__(256) void conv_pool_lrelu_l5(
    const float* __restrict__ in,   // [B,32,2,2,2]
    const float* __restrict__ w,    // [64,32,3,3,3]
    const float* __restrict__ bias, // [64]
    float* __restrict__ out,        // [B,64]
    int B)
{
    constexpr int CI = 32;
    __shared__ float sm[4 * CI * 64];
    const int t = threadIdx.x;
    const int b0 = blockIdx.x * 4;

    for (int i = t; i < 4 * CI * 64; i += 256) {
        const int x = i % 4;
        const int y = (i / 4) % 4;
        const int z = (i / 16) % 4;
        const int ci = (i / 64) % CI;
        const int bl = i / (64 * CI);
        const int gx = x - 1, gy = y - 1, gz = z - 1;
        float v = 0.f;
        if ((unsigned)gx < 2u && (unsigned)gy < 2u && (unsigned)gz < 2u)
            v = in[((b0 + bl) * CI + ci) * 8 + (gz * 2 + gy) * 2 + gx];
        sm[i] = v;
    }
    __syncthreads();

    const int co = t % 64;
    const int bl = t / 64;
    float acc[8];
#pragma unroll
    for (int p = 0; p < 8; ++p) acc[p] = 0.f;

#pragma unroll 1
    for (int ci = 0; ci < CI; ++ci) {
        const float* sp_ = &sm[(bl * CI + ci) * 64];
        float v[4][4][4];
#pragma unroll
        for (int dz = 0; dz < 4; ++dz)
#pragma unroll
            for (int dy = 0; dy < 4; ++dy)
#pragma unroll
                for (int dx = 0; dx < 4; ++dx)
                    v[dz][dy][dx] = sp_[(dz * 4 + dy) * 4 + dx];
        const float* wp = w + (long)(co * CI + ci) * 27;
#pragma unroll
        for (int kz = 0; kz < 3; ++kz)
#pragma unroll
            for (int ky = 0; ky < 3; ++ky)
#pragma unroll
                for (int kx = 0; kx < 3; ++kx) {
                    const float wv = wp[kz * 9 + ky * 3 + kx];
#pragma unroll
                    for (int pz = 0; pz < 2; ++pz)
#pragma unroll
                        for (int py = 0; py < 2; ++py)
#pragma unroll
                            for (int px = 0; px < 2; ++px)
                                acc[pz * 4 + py * 2 + px] +=
                                    v[pz + kz][py + ky][px + kx] * wv;
                }
    }

    float m = acc[0];
#pragma unroll
    for (int p = 1; p < 8; ++p) m = fmaxf(m, acc[p]);
    m += bias[co];
    out[(b0 + bl) * 64 + co] = lrelu(m);
}

// 6 parallel heads: [B,64] -> 32 -> 16 -> 4, lrelu each, then L2-normalize.
__global__ __launch_bounds__(256) void fc_heads(
    const float* __restrict__ feat,
    const float* __restrict__ W1, const float* __restrict__ b1,
    const float* __restrict__ W2, const float* __restrict__ b2,
    const float* __restrict__ W3, const float* __restrict__ b3,
    float* __restrict__ out, int B)
{
    const int tid = blockIdx.x * 256 + threadIdx.x;
    if (tid >= 6 * B) return;
    const int b = tid % B;
    const int h = tid / B;

    float f[64];
#pragma unroll
    for (int k = 0; k < 64; ++k) f[k] = feat[b * 64 + k];

    float h1[32];
#pragma unroll 1
    for (int j = 0; j < 32; ++j) {
        float s = b1[h * 32 + j];
#pragma unroll
        for (int k = 0; k < 64; ++k) s += f[k] * W1[(h * 64 + k) * 32 + j];
        h1[j] = lrelu(s);
    }
    float h2[16];
#pragma unroll 1
    for (int j = 0; j < 16; ++j) {
        float s = b2[h * 16 + j];
#pragma unroll
        for (int k = 0; k < 32; ++k) s += h1[k] * W2[(h * 32 + k) * 16 + j];
        h2[j] = lrelu(s);
    }
    float h3[4];
#pragma unroll
    for (int j = 0; j < 4; ++j) {
        float s = b3[h * 4 + j];
#pragma unroll
        for (int k = 0; k < 16; ++k) s += h2[k] * W3[(h * 16 + k) * 4 + j];
        h3[j] = lrelu(s);
    }
    const float n = sqrtf(h3[0] * h3[0] + h3[1] * h3[1] +
                          h3[2] * h3[2] + h3[3] * h3[3]);
    const float inv = 1.f / n;
#pragma unroll
    for (int q = 0; q < 4; ++q) out[(b * 6 + h) * 4 + q] = h3[q] * inv;
}

extern "C" void kernel_launch(void* const* d_in, const int* in_sizes, int n_in,
                              void* d_out, int out_size, void* d_ws, size_t ws_size,
                              hipStream_t stream)
{
    const float* voxel = (const float*)d_in[0];
    const float* cw1 = (const float*)d_in[1];  const float* cb1 = (const float*)d_in[2];
    const float* cw2 = (const float*)d_in[3];  const float* cb2 = (const float*)d_in[4];
    const float* cw3 = (const float*)d_in[5];  const float* cb3 = (const float*)d_in[6];
    const float* cw4 = (const float*)d_in[7];  const float* cb4 = (const float*)d_in[8];
    const float* cw5 = (const float*)d_in[9];  const float* cb5 = (const float*)d_in[10];
    const float* W1  = (const float*)d_in[11]; const float* b1  = (const float*)d_in[12];
    const float* W2  = (const float*)d_in[13]; const float* b2  = (const float*)d_in[14];
    const float* W3  = (const float*)d_in[15]; const float* b3  = (const float*)d_in[16];
    float* out = (float*)d_out;

    const int B = 1024;
    float* buf1 = (float*)d_ws;              // [B,4,16^3]
    float* buf2 = buf1 + 16777216;           // [B,8,8^3]
    float* buf3 = buf2 + 4194304;            // [B,16,4^3]
    float* buf4 = buf3 + 1048576;            // [B,32,2^3]
    float* buf5 = buf4 + 262144;             // [B,64]

    // L1: 1->4, 32^3->16^3. ZT=2, PZT=2, CPT=4. 1*1*(1*256)=256 ✓ LDS 32.6KB
    conv_pool_lds2<1, 4, 32, 2, 2, 4, 1><<<1024 * 8, 256, 0, stream>>>(voxel, cw1, cb1, buf1, B);
    // L2: 4->8, 16^3->8^3. ZT=2, CPT=4. 1*2*(2*64)=256 ✓ LDS 41.5KB
    conv_pool_lds2<4, 8, 16, 2, 1, 4, 1><<<1024 * 4, 256, 0, stream>>>(buf1, cw2, cb2, buf2, B);
    // L3: 8->16, 8^3->4^3. ZT=4, CPT=4. 1*4*(4*16)=256 ✓ LDS 51.2KB
    conv_pool_lds2<8, 16, 8, 4, 1, 4, 1><<<1024, 256, 0, stream>>>(buf2, cw3, cb3, buf3, B);
    // L4: 16->32, 4^3->2^3. ZT=2, CPT=2, BPB=2. 2*16*(2*4)=256 ✓ LDS 55.3KB
    conv_pool_lds2<16, 32, 4, 2, 1, 2, 2><<<512, 256, 0, stream>>>(buf3, cw4, cb4, buf4, B);
    // L5: 32->64, 2^3->1. 4 b/block.
    conv_pool_lrelu_l5<<<256, 256, 0, stream>>>(buf4, cw5, cb5, buf5, B);
    // FC heads
    fc_heads<<<24, 256, 0, stream>>>(buf5, W1, b1, W2, b2, W3, b3, out, B);
}